// Round 1
// baseline (264.177 us; speedup 1.0000x reference)
//
#include <hip/hip_runtime.h>

// ---------------------------------------------------------------------------
// Compile-time real-spherical-harmonic Clebsch-Gordan tables (constexpr),
// identical math to the reference's _cg_complex / _u / _cg_real.
// ---------------------------------------------------------------------------
namespace cgx {

struct Cplx { double re, im; };

constexpr Cplx cmul(Cplx a, Cplx b) {
  return Cplx{a.re * b.re - a.im * b.im, a.re * b.im + a.im * b.re};
}

constexpr double cfact(int n) {
  double r = 1.0;
  for (int i = 2; i <= n; i++) r *= (double)i;
  return r;
}

constexpr double cabs_(double x) { return x < 0.0 ? -x : x; }

constexpr double csqrt_(double x) {
  if (x <= 0.0) return 0.0;
  double g = x > 1.0 ? x : 1.0;
  for (int it = 0; it < 80; ++it) g = 0.5 * (g + x / g);
  return g;
}

struct CGC { double v[5][5][9]; };

constexpr CGC cg_complex(int l1, int l2, int l3) {
  CGC C{};
  for (int m1 = -l1; m1 <= l1; m1++) {
    for (int m2 = -l2; m2 <= l2; m2++) {
      int m3 = m1 + m2;
      if (m3 < -l3 || m3 > l3) continue;
      double pre = csqrt_((double)(2 * l3 + 1) * cfact(l1 + l2 - l3) *
                          cfact(l1 - l2 + l3) * cfact(-l1 + l2 + l3) /
                          cfact(l1 + l2 + l3 + 1));
      pre *= csqrt_(cfact(l3 + m3) * cfact(l3 - m3) * cfact(l1 - m1) *
                    cfact(l1 + m1) * cfact(l2 - m2) * cfact(l2 + m2));
      double s = 0.0;
      for (int k = 0; k <= l1 + l2 - l3; k++) {
        int d1 = l1 + l2 - l3 - k, d2 = l1 - m1 - k, d3 = l2 + m2 - k;
        int d4 = l3 - l2 + m1 + k, d5 = l3 - l1 - m2 + k;
        if (d1 < 0 || d2 < 0 || d3 < 0 || d4 < 0 || d5 < 0) continue;
        double d = cfact(k) * cfact(d1) * cfact(d2) * cfact(d3) * cfact(d4) * cfact(d5);
        s += ((k & 1) ? -1.0 : 1.0) / d;
      }
      C.v[m1 + l1][m2 + l2][m3 + l3] = pre * s;
    }
  }
  return C;
}

struct UMat { Cplx v[9][9]; };

constexpr UMat umat(int l) {
  UMat U{};
  double is2 = csqrt_(0.5);
  U.v[l][l] = Cplx{1.0, 0.0};
  for (int m = 1; m <= l; m++) {
    double sgn = (m & 1) ? -1.0 : 1.0;
    U.v[l + m][l + m] = Cplx{sgn * is2, 0.0};
    U.v[l + m][l - m] = Cplx{is2, 0.0};
    U.v[l - m][l - m] = Cplx{0.0, is2};
    U.v[l - m][l + m] = Cplx{0.0, -sgn * is2};
  }
  return U;
}

struct CGR { float v[5][5][9]; };

constexpr CGR cg_real(int l1, int l2, int l3) {
  CGC C = cg_complex(l1, l2, l3);
  UMat U1 = umat(l1), U2 = umat(l2), U3 = umat(l3);
  double re[5][5][9]{}, im[5][5][9]{};
  double maxre = 0.0, maxim = 0.0;
  for (int a = 0; a < 2 * l1 + 1; a++)
    for (int b = 0; b < 2 * l2 + 1; b++)
      for (int c = 0; c < 2 * l3 + 1; c++) {
        double ar = 0.0, ai = 0.0;
        for (int i = 0; i < 2 * l1 + 1; i++) {
          Cplx u1 = U1.v[a][i];
          if (u1.re == 0.0 && u1.im == 0.0) continue;
          for (int j = 0; j < 2 * l2 + 1; j++) {
            Cplx u2 = U2.v[b][j];
            if (u2.re == 0.0 && u2.im == 0.0) continue;
            int k0 = (i - l1) + (j - l2) + l3;
            if (k0 < 0 || k0 > 2 * l3) continue;
            double cv = C.v[i][j][k0];
            if (cv == 0.0) continue;
            Cplx u3 = U3.v[c][k0];
            if (u3.re == 0.0 && u3.im == 0.0) continue;
            Cplx u12 = cmul(u1, u2);
            Cplx t = cmul(u12, Cplx{u3.re, -u3.im});
            ar += t.re * cv;
            ai += t.im * cv;
          }
        }
        re[a][b][c] = ar;
        im[a][b][c] = ai;
        if (cabs_(ar) > maxre) maxre = cabs_(ar);
        if (cabs_(ai) > maxim) maxim = cabs_(ai);
      }
  CGR R{};
  bool useim = maxim > maxre;
  for (int a = 0; a < 2 * l1 + 1; a++)
    for (int b = 0; b < 2 * l2 + 1; b++)
      for (int c = 0; c < 2 * l3 + 1; c++)
        R.v[a][b][c] = (float)(useim ? im[a][b][c] : re[a][b][c]);
  return R;
}

// Effective table for the kernel. Folds the reference's 0.5 factor and
// cleans fp noise so `cv != 0` is a clean compile-time sparsity test.
//  mode 0: plain cg(l1,l2,lo)
//  mode 1: triangle-folded (self pair, products p[i][j] defined for i<=j only;
//          folding x_i x_j == x_j x_i is unconditionally valid)
//  mode 2: transposed cg(l2,l1,lo)  (runtime fallback for swapped couplings)
constexpr CGR cg_table(int l1, int l2, int l3, int mode) {
  CGR R{};
  if (mode == 2) {
    CGR B = cg_real(l2, l1, l3);
    for (int i = 0; i < 2 * l1 + 1; i++)
      for (int j = 0; j < 2 * l2 + 1; j++)
        for (int k = 0; k < 2 * l3 + 1; k++)
          R.v[i][j][k] = B.v[j][i][k];
  } else {
    R = cg_real(l1, l2, l3);
    if (mode == 1) {
      for (int i = 0; i < 2 * l1 + 1; i++)
        for (int j = 0; j < i; j++)
          for (int k = 0; k < 2 * l3 + 1; k++) {
            R.v[j][i][k] += R.v[i][j][k];  // fold lower into upper triangle
            R.v[i][j][k] = 0.0f;
          }
    }
  }
  for (int i = 0; i < 5; i++)
    for (int j = 0; j < 5; j++)
      for (int k = 0; k < 9; k++) {
        double v = 0.5 * (double)R.v[i][j][k];  // reference's 0.5*mix factor
        R.v[i][j][k] = (cabs_(v) < 1e-6) ? 0.0f : (float)v;
      }
  return R;
}

constexpr bool all_zero(const CGR& t) {
  for (int i = 0; i < 5; i++)
    for (int j = 0; j < 5; j++)
      for (int k = 0; k < 9; k++)
        if (t.v[i][j][k] != 0.0f) return false;
  return true;
}

// Sign s with cg(l2,l1,lo)[j][i][k] == s * cg(l1,l2,lo)[i][j][k]; 0 if neither
// sign matches (then the caller falls back to two separate contractions).
constexpr int swap_sign(int l1, int l2, int l3) {
  CGR A = cg_real(l1, l2, l3);
  CGR B = cg_real(l2, l1, l3);
  bool plus = true, minus = true;
  for (int i = 0; i < 2 * l1 + 1; i++)
    for (int j = 0; j < 2 * l2 + 1; j++)
      for (int k = 0; k < 2 * l3 + 1; k++) {
        double a = (double)A.v[i][j][k], b = (double)B.v[j][i][k];
        if (cabs_(b - a) > 1e-5) plus = false;
        if (cabs_(b + a) > 1e-5) minus = false;
      }
  return plus ? 1 : (minus ? -1 : 0);
}

}  // namespace cgx

// ---------------------------------------------------------------------------
// float2 helpers: 2 channels per thread, 8 B/lane loads/stores.
// ---------------------------------------------------------------------------
typedef float2 f2;

__device__ __forceinline__ f2 f2mul(f2 a, f2 b) { return make_float2(a.x * b.x, a.y * b.y); }
__device__ __forceinline__ f2 f2add(f2 a, f2 b) { return make_float2(a.x + b.x, a.y + b.y); }
__device__ __forceinline__ f2 f2sub(f2 a, f2 b) { return make_float2(a.x - b.x, a.y - b.y); }

// out[k] += w * sum_ij cg[i][j][k] * p[i][j]; CG folds to literals, zero terms
// are eliminated at compile time; all-zero couplings compile to nothing.
template <int L1, int L2, int LO, int MODE>
__device__ __forceinline__ void couple(const f2 (&p)[2 * L1 + 1][2 * L2 + 1],
                                       f2 w, f2 (&o)[2 * LO + 1]) {
  constexpr cgx::CGR tt = cgx::cg_table(L1, L2, LO, MODE);
  if constexpr (!cgx::all_zero(tt)) {
#pragma unroll
    for (int k = 0; k < 2 * LO + 1; k++) {
      f2 tp = make_float2(0.0f, 0.0f);
      bool any = false;
#pragma unroll
      for (int i = 0; i < 2 * L1 + 1; i++)
#pragma unroll
        for (int j = 0; j < 2 * L2 + 1; j++) {
          const float cv = tt.v[i][j][k];
          if (cv != 0.0f) {  // folds: constant condition after unroll
            tp.x = fmaf(cv, p[i][j].x, tp.x);
            tp.y = fmaf(cv, p[i][j].y, tp.y);
            any = true;
          }
        }
      if (any) {
        o[k].x = fmaf(w.x, tp.x, o[k].x);
        o[k].y = fmaf(w.y, tp.y, o[k].y);
      }
    }
  }
}

// Merged swapped-operand pair: contribution wA*cg(L1,L2) + wB*cg(L2,L1)^T.
// If the compile-time-verified swap symmetry holds (it does analytically:
// s = (-1)^(L1+L2+LO)), this is ONE contraction with weight wA + s*wB.
template <int L1, int L2, int LO>
__device__ __forceinline__ void couple_pair(const f2 (&p)[2 * L1 + 1][2 * L2 + 1],
                                            f2 wA, f2 wB, f2 (&o)[2 * LO + 1]) {
  constexpr int S = cgx::swap_sign(L1, L2, LO);
  if constexpr (S == 1) {
    couple<L1, L2, LO, 0>(p, f2add(wA, wB), o);
  } else if constexpr (S == -1) {
    couple<L1, L2, LO, 0>(p, f2sub(wA, wB), o);
  } else {  // safe fallback: two separate contractions (never expected)
    couple<L1, L2, LO, 0>(p, wA, o);
    couple<L1, L2, LO, 2>(p, wB, o);
  }
}

// Layout (matches reference):
//  DIM_IN = 1152: x0 @ 0 (1x128), x1 @ 128 (3x128), x2 @ 512 (5x128)
//  DIM_OUT = 3200: o0 @ 0, o1 @ 128, o2 @ 512, o3 @ 1152, o4 @ 2048
//  keep: l=0 @ 0, l=1 @ 128, l=2 @ 256;  mix: 19 couplings x 128, lo-major.

__global__ __launch_bounds__(256) void selfmix_kernel(
    const float* __restrict__ x, const float* __restrict__ keep,
    const float* __restrict__ mix, float* __restrict__ out, int B) {
  int tid = blockIdx.x * 256 + threadIdx.x;
  int b = tid >> 6;        // 64 threads per batch row
  int c = (tid & 63) * 2;  // channel pair (float2)
  if (b >= B) return;

  const float* xb = x + (size_t)b * 1152;
#define LD2(ptr) (*reinterpret_cast<const float2*>(ptr))

  f2 x0 = LD2(xb + c);
  f2 x1[3], x2[5];
#pragma unroll
  for (int m = 0; m < 3; m++) x1[m] = LD2(xb + 128 + m * 128 + c);
#pragma unroll
  for (int m = 0; m < 5; m++) x2[m] = LD2(xb + 512 + m * 128 + c);

  auto lw = [&](int i) { return LD2(mix + i * 128 + c); };

  // accumulators initialized with the keep (skip) path
  f2 k0 = LD2(keep + c), k1 = LD2(keep + 128 + c), k2 = LD2(keep + 256 + c);
  f2 o0[1] = {f2mul(k0, x0)};
  f2 o1[3], o2[5], o3[7], o4[9];
#pragma unroll
  for (int m = 0; m < 3; m++) o1[m] = f2mul(k1, x1[m]);
#pragma unroll
  for (int m = 0; m < 5; m++) o2[m] = f2mul(k2, x2[m]);
#pragma unroll
  for (int m = 0; m < 7; m++) o3[m] = make_float2(0.0f, 0.0f);
#pragma unroll
  for (int m = 0; m < 9; m++) o4[m] = make_float2(0.0f, 0.0f);

  float* ob = out + (size_t)b * 3200;
#define ST2(ptr, v) (*reinterpret_cast<float2*>(ptr) = (v))

  // ---- phase 1: x0*x0 -> o0 (coupling idx 0) ----
  {
    f2 p00[1][1] = {{f2mul(x0, x0)}};
    couple<0, 0, 0, 0>(p00, lw(0), o0);
  }

  // ---- phase 2: x1 (x) x1 triangle -> o0, o2; (1,1,1)->o1 is analytic 0 ----
  {
    f2 p11[3][3];
#pragma unroll
    for (int i = 0; i < 3; i++)
#pragma unroll
      for (int j = 0; j < 3; j++)
        if (j >= i) p11[i][j] = f2mul(x1[i], x1[j]);
    couple<1, 1, 0, 1>(p11, lw(1), o0);
    couple<1, 1, 1, 1>(p11, lw(5), o1);   // antisymmetric: compiles to nothing
    couple<1, 1, 2, 1>(p11, lw(10), o2);
  }

  // ---- phase 3: x0 (x) x1 -> o1 (merged idx 3 + 4) ----
  {
    f2 p01[1][3];
#pragma unroll
    for (int j = 0; j < 3; j++) p01[0][j] = f2mul(x0, x1[j]);
    couple_pair<0, 1, 1>(p01, lw(3), lw(4), o1);
  }

  // ---- phase 4: x1 (x) x2 -> o1, o2, o3 (merged 6+7, 11-13, 15+16) ----
  {
    f2 p12[3][5];
#pragma unroll
    for (int i = 0; i < 3; i++)
#pragma unroll
      for (int j = 0; j < 5; j++) p12[i][j] = f2mul(x1[i], x2[j]);
    couple_pair<1, 2, 1>(p12, lw(6), lw(7), o1);
    couple_pair<1, 2, 3>(p12, lw(15), lw(16), o3);
    couple_pair<1, 2, 2>(p12, lw(11), lw(13), o2);
  }

  // o1 and o3 are final: store early to cut register liveness
#pragma unroll
  for (int m = 0; m < 3; m++) ST2(ob + 128 + m * 128 + c, o1[m]);
#pragma unroll
  for (int m = 0; m < 7; m++) ST2(ob + 1152 + m * 128 + c, o3[m]);

  // ---- phase 5: x0 (x) x2 -> o2 (merged idx 9 + 12) ----
  {
    f2 p02[1][5];
#pragma unroll
    for (int j = 0; j < 5; j++) p02[0][j] = f2mul(x0, x2[j]);
    couple_pair<0, 2, 2>(p02, lw(9), lw(12), o2);
  }

  // ---- phase 6: x2 (x) x2 triangle -> o0, o2, o4; (2,2,1),(2,2,3) are 0 ----
  {
    f2 p22[5][5];
#pragma unroll
    for (int i = 0; i < 5; i++)
#pragma unroll
      for (int j = 0; j < 5; j++)
        if (j >= i) p22[i][j] = f2mul(x2[i], x2[j]);
    couple<2, 2, 0, 1>(p22, lw(2), o0);
    couple<2, 2, 1, 1>(p22, lw(8), o1);   // antisymmetric: compiles to nothing
    couple<2, 2, 2, 1>(p22, lw(14), o2);
    couple<2, 2, 3, 1>(p22, lw(17), o3);  // antisymmetric: compiles to nothing
    couple<2, 2, 4, 1>(p22, lw(18), o4);
  }

  ST2(ob + c, o0[0]);
#pragma unroll
  for (int m = 0; m < 5; m++) ST2(ob + 512 + m * 128 + c, o2[m]);
#pragma unroll
  for (int m = 0; m < 9; m++) ST2(ob + 2048 + m * 128 + c, o4[m]);
#undef LD2
#undef ST2
}

extern "C" void kernel_launch(void* const* d_in, const int* in_sizes, int n_in,
                              void* d_out, int out_size, void* d_ws, size_t ws_size,
                              hipStream_t stream) {
  const float* x = (const float*)d_in[0];
  const float* keep = (const float*)d_in[1];
  const float* mix = (const float*)d_in[2];
  float* out = (float*)d_out;
  int B = in_sizes[0] / 1152;  // 16384
  int total = B * 64;          // 2 channels per thread
  int blocks = (total + 255) / 256;
  selfmix_kernel<<<blocks, 256, 0, stream>>>(x, keep, mix, out, B);
}

// Round 2
// 259.928 us; speedup vs baseline: 1.0163x; 1.0163x over previous
//
#include <hip/hip_runtime.h>

// ---------------------------------------------------------------------------
// Compile-time real-spherical-harmonic Clebsch-Gordan tables (constexpr),
// identical math to the reference's _cg_complex / _u / _cg_real.
// ---------------------------------------------------------------------------
namespace cgx {

struct Cplx { double re, im; };

constexpr Cplx cmul(Cplx a, Cplx b) {
  return Cplx{a.re * b.re - a.im * b.im, a.re * b.im + a.im * b.re};
}

constexpr double cfact(int n) {
  double r = 1.0;
  for (int i = 2; i <= n; i++) r *= (double)i;
  return r;
}

constexpr double cabs_(double x) { return x < 0.0 ? -x : x; }

constexpr double csqrt_(double x) {
  if (x <= 0.0) return 0.0;
  double g = x > 1.0 ? x : 1.0;
  for (int it = 0; it < 80; ++it) g = 0.5 * (g + x / g);
  return g;
}

struct CGC { double v[5][5][9]; };

constexpr CGC cg_complex(int l1, int l2, int l3) {
  CGC C{};
  for (int m1 = -l1; m1 <= l1; m1++) {
    for (int m2 = -l2; m2 <= l2; m2++) {
      int m3 = m1 + m2;
      if (m3 < -l3 || m3 > l3) continue;
      double pre = csqrt_((double)(2 * l3 + 1) * cfact(l1 + l2 - l3) *
                          cfact(l1 - l2 + l3) * cfact(-l1 + l2 + l3) /
                          cfact(l1 + l2 + l3 + 1));
      pre *= csqrt_(cfact(l3 + m3) * cfact(l3 - m3) * cfact(l1 - m1) *
                    cfact(l1 + m1) * cfact(l2 - m2) * cfact(l2 + m2));
      double s = 0.0;
      for (int k = 0; k <= l1 + l2 - l3; k++) {
        int d1 = l1 + l2 - l3 - k, d2 = l1 - m1 - k, d3 = l2 + m2 - k;
        int d4 = l3 - l2 + m1 + k, d5 = l3 - l1 - m2 + k;
        if (d1 < 0 || d2 < 0 || d3 < 0 || d4 < 0 || d5 < 0) continue;
        double d = cfact(k) * cfact(d1) * cfact(d2) * cfact(d3) * cfact(d4) * cfact(d5);
        s += ((k & 1) ? -1.0 : 1.0) / d;
      }
      C.v[m1 + l1][m2 + l2][m3 + l3] = pre * s;
    }
  }
  return C;
}

struct UMat { Cplx v[9][9]; };

constexpr UMat umat(int l) {
  UMat U{};
  double is2 = csqrt_(0.5);
  U.v[l][l] = Cplx{1.0, 0.0};
  for (int m = 1; m <= l; m++) {
    double sgn = (m & 1) ? -1.0 : 1.0;
    U.v[l + m][l + m] = Cplx{sgn * is2, 0.0};
    U.v[l + m][l - m] = Cplx{is2, 0.0};
    U.v[l - m][l - m] = Cplx{0.0, is2};
    U.v[l - m][l + m] = Cplx{0.0, -sgn * is2};
  }
  return U;
}

struct CGR { float v[5][5][9]; };

constexpr CGR cg_real(int l1, int l2, int l3) {
  CGC C = cg_complex(l1, l2, l3);
  UMat U1 = umat(l1), U2 = umat(l2), U3 = umat(l3);
  double re[5][5][9]{}, im[5][5][9]{};
  double maxre = 0.0, maxim = 0.0;
  for (int a = 0; a < 2 * l1 + 1; a++)
    for (int b = 0; b < 2 * l2 + 1; b++)
      for (int c = 0; c < 2 * l3 + 1; c++) {
        double ar = 0.0, ai = 0.0;
        for (int i = 0; i < 2 * l1 + 1; i++) {
          Cplx u1 = U1.v[a][i];
          if (u1.re == 0.0 && u1.im == 0.0) continue;
          for (int j = 0; j < 2 * l2 + 1; j++) {
            Cplx u2 = U2.v[b][j];
            if (u2.re == 0.0 && u2.im == 0.0) continue;
            int k0 = (i - l1) + (j - l2) + l3;
            if (k0 < 0 || k0 > 2 * l3) continue;
            double cv = C.v[i][j][k0];
            if (cv == 0.0) continue;
            Cplx u3 = U3.v[c][k0];
            if (u3.re == 0.0 && u3.im == 0.0) continue;
            Cplx u12 = cmul(u1, u2);
            Cplx t = cmul(u12, Cplx{u3.re, -u3.im});
            ar += t.re * cv;
            ai += t.im * cv;
          }
        }
        re[a][b][c] = ar;
        im[a][b][c] = ai;
        if (cabs_(ar) > maxre) maxre = cabs_(ar);
        if (cabs_(ai) > maxim) maxim = cabs_(ai);
      }
  CGR R{};
  bool useim = maxim > maxre;
  for (int a = 0; a < 2 * l1 + 1; a++)
    for (int b = 0; b < 2 * l2 + 1; b++)
      for (int c = 0; c < 2 * l3 + 1; c++)
        R.v[a][b][c] = (float)(useim ? im[a][b][c] : re[a][b][c]);
  return R;
}

// Effective table: folds the reference's 0.5 factor, cleans fp noise so
// `cv != 0` is a clean compile-time sparsity test.
//  mode 0: plain cg(l1,l2,lo)
//  mode 1: triangle-folded (self pair; products defined for i<=j only)
//  mode 2: transposed cg(l2,l1,lo) (runtime fallback for swapped couplings)
constexpr CGR cg_table(int l1, int l2, int l3, int mode) {
  CGR R{};
  if (mode == 2) {
    CGR B = cg_real(l2, l1, l3);
    for (int i = 0; i < 2 * l1 + 1; i++)
      for (int j = 0; j < 2 * l2 + 1; j++)
        for (int k = 0; k < 2 * l3 + 1; k++)
          R.v[i][j][k] = B.v[j][i][k];
  } else {
    R = cg_real(l1, l2, l3);
    if (mode == 1) {
      for (int i = 0; i < 2 * l1 + 1; i++)
        for (int j = 0; j < i; j++)
          for (int k = 0; k < 2 * l3 + 1; k++) {
            R.v[j][i][k] += R.v[i][j][k];  // fold lower into upper triangle
            R.v[i][j][k] = 0.0f;
          }
    }
  }
  for (int i = 0; i < 5; i++)
    for (int j = 0; j < 5; j++)
      for (int k = 0; k < 9; k++) {
        double v = 0.5 * (double)R.v[i][j][k];  // reference's 0.5*mix factor
        R.v[i][j][k] = (cabs_(v) < 1e-6) ? 0.0f : (float)v;
      }
  return R;
}

constexpr bool all_zero(const CGR& t) {
  for (int i = 0; i < 5; i++)
    for (int j = 0; j < 5; j++)
      for (int k = 0; k < 9; k++)
        if (t.v[i][j][k] != 0.0f) return false;
  return true;
}

// Sign s with cg(l2,l1,lo)[j][i][k] == s * cg(l1,l2,lo)[i][j][k]; 0 if neither
// sign matches (caller falls back to two separate contractions).
constexpr int swap_sign(int l1, int l2, int l3) {
  CGR A = cg_real(l1, l2, l3);
  CGR B = cg_real(l2, l1, l3);
  bool plus = true, minus = true;
  for (int i = 0; i < 2 * l1 + 1; i++)
    for (int j = 0; j < 2 * l2 + 1; j++)
      for (int k = 0; k < 2 * l3 + 1; k++) {
        double a = (double)A.v[i][j][k], b = (double)B.v[j][i][k];
        if (cabs_(b - a) > 1e-5) plus = false;
        if (cabs_(b + a) > 1e-5) minus = false;
      }
  return plus ? 1 : (minus ? -1 : 0);
}

}  // namespace cgx

// ---------------------------------------------------------------------------
// float2 via ext_vector_type so nontemporal builtins lower to dwordx2 nt.
// 2 channels per thread, 8 B/lane; a wave64 covers one full 128-ch row,
// so every load/store instruction is one contiguous 512 B segment.
// ---------------------------------------------------------------------------
typedef float f2 __attribute__((ext_vector_type(2)));

__device__ __forceinline__ f2 vset(float a) { f2 r; r.x = a; r.y = a; return r; }
__device__ __forceinline__ f2 vfma(float c, f2 a, f2 b) {
  return __builtin_elementwise_fma(vset(c), a, b);
}
__device__ __forceinline__ f2 vfma2(f2 w, f2 a, f2 b) {
  return __builtin_elementwise_fma(w, a, b);
}

// out[k] += w * sum_ij cg[i][j][k] * p[i][j]; CG folds to literals, zero terms
// eliminated at compile time; all-zero couplings compile to nothing.
template <int L1, int L2, int LO, int MODE>
__device__ __forceinline__ void couple(const f2 (&p)[2 * L1 + 1][2 * L2 + 1],
                                       f2 w, f2 (&o)[2 * LO + 1]) {
  constexpr cgx::CGR tt = cgx::cg_table(L1, L2, LO, MODE);
  if constexpr (!cgx::all_zero(tt)) {
#pragma unroll
    for (int k = 0; k < 2 * LO + 1; k++) {
      f2 tp = vset(0.0f);
      bool any = false;
#pragma unroll
      for (int i = 0; i < 2 * L1 + 1; i++)
#pragma unroll
        for (int j = 0; j < 2 * L2 + 1; j++) {
          const float cv = tt.v[i][j][k];
          if (cv != 0.0f) {  // folds: constant condition after unroll
            tp = vfma(cv, p[i][j], tp);
            any = true;
          }
        }
      if (any) o[k] = vfma2(w, tp, o[k]);
    }
  }
}

// Merged swapped-operand pair: wA*cg(L1,L2) + wB*cg(L2,L1)^T. Swap symmetry
// (s = (-1)^(L1+L2+LO)) is verified constexpr; one contraction, weight wA+s*wB.
template <int L1, int L2, int LO>
__device__ __forceinline__ void couple_pair(const f2 (&p)[2 * L1 + 1][2 * L2 + 1],
                                            f2 wA, f2 wB, f2 (&o)[2 * LO + 1]) {
  constexpr int S = cgx::swap_sign(L1, L2, LO);
  if constexpr (S == 1) {
    couple<L1, L2, LO, 0>(p, wA + wB, o);
  } else if constexpr (S == -1) {
    couple<L1, L2, LO, 0>(p, wA - wB, o);
  } else {  // safe fallback: two separate contractions (never expected)
    couple<L1, L2, LO, 0>(p, wA, o);
    couple<L1, L2, LO, 2>(p, wB, o);
  }
}

// Layout (matches reference):
//  DIM_IN = 1152: x0 @ 0 (1x128), x1 @ 128 (3x128), x2 @ 512 (5x128)
//  DIM_OUT = 3200: o0 @ 0, o1 @ 128, o2 @ 512, o3 @ 1152, o4 @ 2048
//  keep: l=0 @ 0, l=1 @ 128, l=2 @ 256;  mix: 19 couplings x 128, lo-major.

__global__ __launch_bounds__(256) void selfmix_kernel(
    const float* __restrict__ x, const float* __restrict__ keep,
    const float* __restrict__ mix, float* __restrict__ out, int B) {
  int tid = blockIdx.x * 256 + threadIdx.x;
  int b = tid >> 6;        // 64 threads per batch row
  int c = (tid & 63) * 2;  // channel pair
  if (b >= B) return;

  const float* xb = x + (size_t)b * 1152;
  // x rows are read exactly once across the whole grid -> nontemporal loads
  // (evict-first, don't pollute L2/L3 for the streamed output).
#define LDX(ptr) __builtin_nontemporal_load(reinterpret_cast<const f2*>(ptr))
  // keep/mix are 9.5 KB broadcast to every wave -> cached loads.
#define LDC(ptr) (*reinterpret_cast<const f2*>(ptr))
  // output is streamed, never re-read -> nontemporal stores.
#define STO(ptr, v) __builtin_nontemporal_store((v), reinterpret_cast<f2*>(ptr))

  f2 x0 = LDX(xb + c);
  f2 x1[3], x2[5];
#pragma unroll
  for (int m = 0; m < 3; m++) x1[m] = LDX(xb + 128 + m * 128 + c);
#pragma unroll
  for (int m = 0; m < 5; m++) x2[m] = LDX(xb + 512 + m * 128 + c);

  auto lw = [&](int i) { return LDC(mix + i * 128 + c); };

  // accumulators initialized with the keep (skip) path
  f2 k0 = LDC(keep + c), k1 = LDC(keep + 128 + c), k2 = LDC(keep + 256 + c);
  f2 o0[1] = {k0 * x0};
  f2 o1[3], o2[5], o3[7], o4[9];
#pragma unroll
  for (int m = 0; m < 3; m++) o1[m] = k1 * x1[m];
#pragma unroll
  for (int m = 0; m < 5; m++) o2[m] = k2 * x2[m];
#pragma unroll
  for (int m = 0; m < 7; m++) o3[m] = vset(0.0f);
#pragma unroll
  for (int m = 0; m < 9; m++) o4[m] = vset(0.0f);

  float* ob = out + (size_t)b * 3200;

  // ---- phase 1: x0*x0 -> o0 ----
  {
    f2 p00[1][1] = {{x0 * x0}};
    couple<0, 0, 0, 0>(p00, lw(0), o0);
  }

  // ---- phase 2: x1 (x) x1 triangle -> o0, o2; (1,1,1) is analytic 0 ----
  {
    f2 p11[3][3];
#pragma unroll
    for (int i = 0; i < 3; i++)
#pragma unroll
      for (int j = 0; j < 3; j++)
        if (j >= i) p11[i][j] = x1[i] * x1[j];
    couple<1, 1, 0, 1>(p11, lw(1), o0);
    couple<1, 1, 1, 1>(p11, lw(5), o1);   // antisymmetric: compiles to nothing
    couple<1, 1, 2, 1>(p11, lw(10), o2);
  }

  // ---- phase 3: x0 (x) x1 -> o1 (merged idx 3 + 4) ----
  {
    f2 p01[1][3];
#pragma unroll
    for (int j = 0; j < 3; j++) p01[0][j] = x0 * x1[j];
    couple_pair<0, 1, 1>(p01, lw(3), lw(4), o1);
  }

  // ---- phase 4: x1 (x) x2 -> o1, o2, o3 (merged 6+7, 11+13, 15+16) ----
  {
    f2 p12[3][5];
#pragma unroll
    for (int i = 0; i < 3; i++)
#pragma unroll
      for (int j = 0; j < 5; j++) p12[i][j] = x1[i] * x2[j];
    couple_pair<1, 2, 1>(p12, lw(6), lw(7), o1);
    couple_pair<1, 2, 3>(p12, lw(15), lw(16), o3);
    couple_pair<1, 2, 2>(p12, lw(11), lw(13), o2);
  }

  // o1 and o3 are final: store early to cut register liveness
#pragma unroll
  for (int m = 0; m < 3; m++) STO(ob + 128 + m * 128 + c, o1[m]);
#pragma unroll
  for (int m = 0; m < 7; m++) STO(ob + 1152 + m * 128 + c, o3[m]);

  // ---- phase 5: x0 (x) x2 -> o2 (merged idx 9 + 12) ----
  {
    f2 p02[1][5];
#pragma unroll
    for (int j = 0; j < 5; j++) p02[0][j] = x0 * x2[j];
    couple_pair<0, 2, 2>(p02, lw(9), lw(12), o2);
  }

  // ---- phase 6: x2 (x) x2 triangle -> o0, o2, o4; (2,2,1),(2,2,3) are 0 ----
  {
    f2 p22[5][5];
#pragma unroll
    for (int i = 0; i < 5; i++)
#pragma unroll
      for (int j = 0; j < 5; j++)
        if (j >= i) p22[i][j] = x2[i] * x2[j];
    couple<2, 2, 0, 1>(p22, lw(2), o0);
    couple<2, 2, 1, 1>(p22, lw(8), o1);   // antisymmetric: compiles to nothing
    couple<2, 2, 2, 1>(p22, lw(14), o2);
    couple<2, 2, 3, 1>(p22, lw(17), o3);  // antisymmetric: compiles to nothing
    couple<2, 2, 4, 1>(p22, lw(18), o4);
  }

  STO(ob + c, o0[0]);
#pragma unroll
  for (int m = 0; m < 5; m++) STO(ob + 512 + m * 128 + c, o2[m]);
#pragma unroll
  for (int m = 0; m < 9; m++) STO(ob + 2048 + m * 128 + c, o4[m]);
#undef LDX
#undef LDC
#undef STO
}

extern "C" void kernel_launch(void* const* d_in, const int* in_sizes, int n_in,
                              void* d_out, int out_size, void* d_ws, size_t ws_size,
                              hipStream_t stream) {
  const float* x = (const float*)d_in[0];
  const float* keep = (const float*)d_in[1];
  const float* mix = (const float*)d_in[2];
  float* out = (float*)d_out;
  int B = in_sizes[0] / 1152;  // 16384
  int total = B * 64;          // 2 channels per thread
  int blocks = (total + 255) / 256;
  selfmix_kernel<<<blocks, 256, 0, stream>>>(x, keep, mix, out, B);
}